// Round 10
// baseline (379.536 us; speedup 1.0000x reference)
//
#include <hip/hip_runtime.h>
#include <hip/hip_bf16.h>

// Correlation, MAX_DISP=4, via bf16 MFMA Gram tiles (verified layouts only).
// out[b, dx*9+dy, h, w] = mean_c x1[b,c,h,w]*x2[b,c,h+dx-4,w+dy-4]
// x1,x2: (8,64,256,256) fp32. out: (8,81,256,256) fp32.
//
// WG = (b, h, w-quarter of 64), 256 thr = 4 waves; wave wv owns p-tile
// [w0+16wv, +16). For each dx (x2 row h+dx-4) and two q-tiles (col offsets
// -4 and +12): D[m][n] = sum_c x1[c][p+m]*x2row[c][q+n] via
// mfma_f32_16x16x32_bf16; dy = n-m (left) / n-m+16 (right).
// LDS: k-major packed k-pairs, lds[kpair][w] = u32(bf16 c=2kp, bf16 c=2kp+1).
//   A/B fragment reg r = ds_read_b32 at [(lane>>4)*4+r][base+(lane&15)]
//   (k = (lane>>4)*8 + 2r + {0,1} -- the m97-verified k-contiguous layout).
// C/D layout (m89): col = lane&15 = n, row = (lane>>4)*4+reg = m.
// K=64 as 2 passes of 32ch. Strides 68/84 dw: lane-group offset = 16 mod 32
// -> 2-way bank alias (free); uint4 staging writes, coalesced, aligned.
// XCD swizzle: b = blockIdx&7 (one batch per XCD).

namespace {
constexpr int kC  = 64;
constexpr int kH  = 256;
constexpr int kW  = 256;
constexpr int kHW = kH * kW;
constexpr int kD  = 9;
constexpr int kX1Str  = 68;              // dw per kpair row (x1), 16 rows
constexpr int kX2Str  = 84;              // dw per kpair row (x2)
constexpr int kX2Blk  = 16 * kX2Str;     // 1344 dw per x2 source row
constexpr int kX2Base = 16 * kX1Str;     // 1088
constexpr int kLdsDw  = kX2Base + kD * kX2Blk;  // 13184 dw = 52736 B
}  // namespace

using short8 = __attribute__((ext_vector_type(8))) short;
using f32x4  = __attribute__((ext_vector_type(4))) float;

__device__ __forceinline__ unsigned pkbf(float lo, float hi) {
  const unsigned short a =
      __builtin_bit_cast(unsigned short, __float2bfloat16(lo));
  const unsigned short b =
      __builtin_bit_cast(unsigned short, __float2bfloat16(hi));
  return (unsigned)a | ((unsigned)b << 16);
}

__global__ __launch_bounds__(256) void corr_mfma(
    const float* __restrict__ x1, const float* __restrict__ x2,
    float* __restrict__ out) {
  __shared__ __attribute__((aligned(16))) unsigned lds[kLdsDw];
  float* ldsf = (float*)lds;  // epilogue alias (81*68 dw < kLdsDw)

  const int b    = blockIdx.x & 7;   // batch -> XCD (round-robin)
  const int slot = blockIdx.x >> 3;
  const int h    = slot >> 2;
  const int wq   = slot & 3;
  const int w0   = wq * 64;

  const int tid  = (int)threadIdx.x;
  const int wv   = tid >> 6;   // wave = p-tile (0..3)
  const int lane = tid & 63;
  const int lg   = lane >> 4;  // k-group
  const int ln   = lane & 15;  // row/col within tile

  f32x4 acc[kD][2];
#pragma unroll
  for (int dx = 0; dx < kD; ++dx)
#pragma unroll
    for (int qt = 0; qt < 2; ++qt) acc[dx][qt] = (f32x4)0.0f;

  // x1 staging role: item = tid -> kpair p1, w-quad w41
  const int p1 = tid >> 4, w41 = tid & 15;

#pragma unroll 1
  for (int pass = 0; pass < 2; ++pass) {
    const int c0 = pass * 32;

    // ---- stage x1: 16 kpair x 64 w ----
    {
      const float* s1 =
          x1 + ((size_t)(b * kC + c0 + 2 * p1) * kH + h) * kW + w0 + 4 * w41;
      const float4 v0 = *(const float4*)s1;
      const float4 v1 = *(const float4*)(s1 + kHW);
      uint4 q;
      q.x = pkbf(v0.x, v1.x); q.y = pkbf(v0.y, v1.y);
      q.z = pkbf(v0.z, v1.z); q.w = pkbf(v0.w, v1.w);
      *(uint4*)&lds[p1 * kX1Str + 4 * w41] = q;
    }
    // ---- stage x2: 9 r x 16 kpair x 20 w-quads (cols w0-4 .. w0+75) ----
#pragma unroll 1
    for (int i = 0; i < 12; ++i) {
      const int s = tid + 256 * i;
      if (s < 2880) {
        const int w4 = s % 20;
        const int rest = s / 20;
        const int p = rest & 15;
        const int r = rest >> 4;
        const int g = h + r - 4;
        const int w = w0 - 4 + 4 * w4;
        uint4 q = make_uint4(0u, 0u, 0u, 0u);
        if (g >= 0 && g < kH && w >= 0 && w <= kW - 4) {
          const float* s2 =
              x2 + ((size_t)(b * kC + c0 + 2 * p) * kH + g) * kW + w;
          const float4 v0 = *(const float4*)s2;
          const float4 v1 = *(const float4*)(s2 + kHW);
          q.x = pkbf(v0.x, v1.x); q.y = pkbf(v0.y, v1.y);
          q.z = pkbf(v0.z, v1.z); q.w = pkbf(v0.w, v1.w);
        }
        *(uint4*)&lds[kX2Base + r * kX2Blk + p * kX2Str + 4 * w4] = q;
      }
    }
    __syncthreads();

    // ---- compute: A once, then 9 dx x 2 q-tiles ----
    union Frag { unsigned u[4]; short8 s; };
    Frag fa;
#pragma unroll
    for (int r = 0; r < 4; ++r)
      fa.u[r] = lds[(lg * 4 + r) * kX1Str + wv * 16 + ln];

#pragma unroll
    for (int dx = 0; dx < kD; ++dx) {
      const int rb = kX2Base + dx * kX2Blk;
#pragma unroll
      for (int qt = 0; qt < 2; ++qt) {
        const int qb = wv * 16 + qt * 16 + ln;  // q index 0..79
        Frag fb;
#pragma unroll
        for (int r = 0; r < 4; ++r)
          fb.u[r] = lds[rb + (lg * 4 + r) * kX2Str + qb];
        acc[dx][qt] = __builtin_amdgcn_mfma_f32_16x16x32_bf16(
            fa.s, fb.s, acc[dx][qt], 0, 0, 0);
      }
    }
    __syncthreads();
  }

  // ---- epilogue: diagonal extract via LDS, then coalesced store ----
  // D[m][n]: m = lg*4 + reg (p), n = ln (q). left: dy = n-m; right: +16.
  const float inv = 1.0f / 64.0f;
#pragma unroll
  for (int dx = 0; dx < kD; ++dx)
#pragma unroll
    for (int r = 0; r < 4; ++r) {
      const int m = lg * 4 + r;
      const int dyL = ln - m;
      if (dyL >= 0 && dyL <= 8)
        ldsf[(dx * 9 + dyL) * 68 + wv * 16 + m] = acc[dx][0][r] * inv;
      const int dyR = ln - m + 16;
      if (dyR <= 8)
        ldsf[(dx * 9 + dyR) * 68 + wv * 16 + m] = acc[dx][1][r] * inv;
    }
  __syncthreads();

#pragma unroll
  for (int i = 0; i < 6; ++i) {
    const int s = tid + 256 * i;
    if (s < 81 * 16) {
      const int dd = s >> 4, w4 = s & 15;
      const float4 v = *(const float4*)&ldsf[dd * 68 + 4 * w4];
      *(float4*)(out + (((size_t)b * 81 + dd) * kH + h) * kW + w0 + 4 * w4) = v;
    }
  }
}

extern "C" void kernel_launch(void* const* d_in, const int* in_sizes, int n_in,
                              void* d_out, int out_size, void* d_ws, size_t ws_size,
                              hipStream_t stream) {
  const float* x1 = (const float*)d_in[0];
  const float* x2 = (const float*)d_in[1];
  float* out = (float*)d_out;
  const int grid = 8 * kH * 4;  // (b, h, w-quarter)
  corr_mfma<<<grid, 256, 0, stream>>>(x1, x2, out);
}